// Round 1
// baseline (741.880 us; speedup 1.0000x reference)
//
#include <hip/hip_runtime.h>
#include <cfloat>
#include <climits>

// Problem: layer_out = x@W^T + b; first-diff pooling over x; MLP encoder;
// nearest-key lookup; per-sample replace-all epilogue.
// B=4 S=2048 D_IN=D_OUT=4096 ENC=256 K=2048, fp32 in/out.

typedef unsigned short u16;
typedef unsigned int   u32;
typedef __attribute__((ext_vector_type(8))) short bf16x8;   // 8 bf16 in 4 VGPRs
typedef __attribute__((ext_vector_type(4))) float f32x4;
typedef __attribute__((address_space(3))) u32 as3u32;
typedef const __attribute__((address_space(1))) u32 as1u32;

#define NB 4
#define NS 2048
#define ND 4096
#define NE 256
#define NK 2048
#define NROWS (NB * NS)   // 8192

// ---- workspace layout (bytes) ----
#define OFF_XB     ((size_t)0)            // 8192*4096 bf16 = 64 MiB
#define OFF_WB     ((size_t)67108864)     // 4096*4096 bf16 = 32 MiB
#define OFF_FLAGS  ((size_t)100663296)    // 8192 int
#define OFF_FIRST  ((size_t)100696064)    // 4 int
#define OFF_INV    ((size_t)100696080)    // 4 float
#define OFF_POOLED ((size_t)100696320)    // 4*4096 float (memset to 0 each call)
#define OFF_H      ((size_t)100761856)    // 4*256 float
#define OFF_Q      ((size_t)100765952)    // 4*256 float
#define OFF_CD2    ((size_t)100770048)    // 32*4 float
#define OFF_CIDX   ((size_t)100770560)    // 32*4 int
#define OFF_HIT    ((size_t)100771072)    // 4 int
#define OFF_CHOSEN ((size_t)100771088)    // 4 int

__device__ __forceinline__ void gld_lds16(const u16* g, u16* l) {
  __builtin_amdgcn_global_load_lds((as1u32*)g, (as3u32*)l, 16, 0, 0);
}

__device__ __forceinline__ u16 f2bf(float f) {   // RNE fp32 -> bf16
  union { float f; u32 u; } v; v.f = f;
  u32 r = v.u + 0x7fffu + ((v.u >> 16) & 1u);
  return (u16)(r >> 16);
}

__device__ __forceinline__ void mfma_bf16(f32x4& acc, bf16x8 a, bf16x8 b) {
  asm("v_mfma_f32_16x16x32_bf16 %0, %1, %2, %0" : "+v"(acc) : "v"(a), "v"(b));
}

// ---- K1: convert x and W to bf16; per-row "differs from previous row" flags ----
// grid 12288 blocks x 256 thr. rows [0,8192): x rows (b,s); rows [8192,12288): W rows.
__global__ __launch_bounds__(256) void k_convert(
    const float* __restrict__ x, const float* __restrict__ W,
    u16* __restrict__ xb, u16* __restrict__ wb, int* __restrict__ flags)
{
  int r = blockIdx.x;
  int tid = threadIdx.x;
  bool isX = r < NROWS;
  int s = r & (NS - 1);
  const float* src;
  u16* dst;
  if (isX) { src = x + (size_t)r * ND; dst = xb + (size_t)r * ND; }
  else     { int wr = r - NROWS; src = W + (size_t)wr * ND; dst = wb + (size_t)wr * ND; }

  const float4* s4 = (const float4*)src;
  int b4 = tid * 4;                    // 16 floats per thread
  float4 v[4];
#pragma unroll
  for (int i = 0; i < 4; i++) v[i] = s4[b4 + i];

  bool d = false;
  if (isX && s > 0) {
    const float4* p4 = s4 - (ND / 4);  // previous row
#pragma unroll
    for (int i = 0; i < 4; i++) {
      float4 p = p4[b4 + i];
      d = d || (v[i].x != p.x) || (v[i].y != p.y) || (v[i].z != p.z) || (v[i].w != p.w);
    }
  }

  u16 t[16];
#pragma unroll
  for (int i = 0; i < 4; i++) {
    t[i*4+0] = f2bf(v[i].x); t[i*4+1] = f2bf(v[i].y);
    t[i*4+2] = f2bf(v[i].z); t[i*4+3] = f2bf(v[i].w);
  }
  uint4* d4 = (uint4*)(dst + (size_t)tid * 16);
  d4[0] = *(const uint4*)&t[0];
  d4[1] = *(const uint4*)&t[8];

  if (isX) {
    __shared__ int sf;
    if (tid == 0) sf = 0;
    __syncthreads();
    if (__any((int)d) && (tid & 63) == 0) atomicOr(&sf, 1);
    __syncthreads();
    if (tid == 0) flags[r] = (s == 0) ? 0 : sf;
  }
}

// ---- K2: per-sample first-diff position + 1/count ----
__global__ __launch_bounds__(256) void k_first(
    const int* __restrict__ flags, int* __restrict__ first, float* __restrict__ inv)
{
  __shared__ int red[256];
  int tid = threadIdx.x;
  for (int b = 0; b < NB; b++) {
    int best = INT_MAX;
    for (int j = 1 + tid; j < NS; j += 256)
      if (flags[b * NS + j] && j < best) best = j;
    red[tid] = best;
    __syncthreads();
    for (int st = 128; st > 0; st >>= 1) {
      if (tid < st && red[tid + st] < red[tid]) red[tid] = red[tid + st];
      __syncthreads();
    }
    if (tid == 0) {
      int f = red[0];
      if (f == INT_MAX) f = 0;
      if (f == 1) f = 0;
      first[b] = f;
      inv[b] = 1.0f / (float)(NS - f);
    }
    __syncthreads();
  }
}

// ---- K3: masked pooled sums (fp32, from original x) ----
// grid 256 blocks (b in [0,4) x 64 s-tiles of 32 rows) x 256 thr; atomicAdd into pooled.
__global__ __launch_bounds__(256) void k_pool(
    const float* __restrict__ x, const int* __restrict__ first, float* __restrict__ pooled)
{
  int b = blockIdx.x >> 6;
  int tile = blockIdx.x & 63;
  int f = first[b];
  int s0 = tile * 32;
  int tid = threadIdx.x;
  float acc[16];
#pragma unroll
  for (int k = 0; k < 16; k++) acc[k] = 0.f;
  const float* base = x + ((size_t)b * NS + s0) * ND + tid * 16;
  for (int i = 0; i < 32; i++) {
    if (s0 + i >= f) {
      const float4* p = (const float4*)(base + (size_t)i * ND);
#pragma unroll
      for (int j = 0; j < 4; j++) {
        float4 v = p[j];
        acc[j*4+0] += v.x; acc[j*4+1] += v.y; acc[j*4+2] += v.z; acc[j*4+3] += v.w;
      }
    }
  }
  float* dst = pooled + b * ND + tid * 16;
#pragma unroll
  for (int k = 0; k < 16; k++) atomicAdd(&dst[k], acc[k]);
}

// ---- K4: h = relu(pooled/cnt @ W1^T + b1) ---- grid 256 blocks (one per output) x 256 thr
__global__ __launch_bounds__(256) void k_enc1(
    const float* __restrict__ pooled, const float* __restrict__ inv,
    const float* __restrict__ W1, const float* __restrict__ b1, float* __restrict__ h)
{
  int o = blockIdx.x, tid = threadIdx.x;
  const float4* w4 = (const float4*)(W1 + (size_t)o * ND);
  float4 w[4];
#pragma unroll
  for (int i = 0; i < 4; i++) w[i] = w4[tid * 4 + i];
  float part[NB];
#pragma unroll
  for (int b = 0; b < NB; b++) {
    const float4* p4 = (const float4*)(pooled + b * ND);
    float s = 0.f;
#pragma unroll
    for (int i = 0; i < 4; i++) {
      float4 p = p4[tid * 4 + i];
      s += w[i].x*p.x + w[i].y*p.y + w[i].z*p.z + w[i].w*p.w;
    }
    part[b] = s;
  }
  __shared__ float red[NB][4];
  int lane = tid & 63, wv = tid >> 6;
#pragma unroll
  for (int b = 0; b < NB; b++) {
    float v = part[b];
    for (int off = 32; off > 0; off >>= 1) v += __shfl_down(v, off);
    if (lane == 0) red[b][wv] = v;
  }
  __syncthreads();
  if (tid < NB) {
    float s = red[tid][0] + red[tid][1] + red[tid][2] + red[tid][3];
    h[tid * NE + o] = fmaxf(s * inv[tid] + b1[o], 0.f);
  }
}

// ---- K5: query = h @ W2^T + b2 ---- 1 block x 256 thr (thread = output o)
__global__ __launch_bounds__(256) void k_enc2(
    const float* __restrict__ h, const float* __restrict__ W2,
    const float* __restrict__ b2, float* __restrict__ q)
{
  __shared__ float hs[NB * NE];
  int tid = threadIdx.x;
  for (int i = tid; i < NB * NE; i += 256) hs[i] = h[i];
  __syncthreads();
  const float* w = W2 + (size_t)tid * NE;
  float bb = b2[tid];
  float s0 = bb, s1 = bb, s2 = bb, s3 = bb;
  for (int e = 0; e < NE; e++) {
    float wv = w[e];
    s0 += hs[e] * wv; s1 += hs[NE + e] * wv;
    s2 += hs[2*NE + e] * wv; s3 += hs[3*NE + e] * wv;
  }
  q[tid] = s0; q[NE + tid] = s1; q[2*NE + tid] = s2; q[3*NE + tid] = s3;
}

// ---- K6: per-block key-distance argmin ---- grid 32 blocks x 64 thr (thread = key)
__global__ __launch_bounds__(64) void k_dist(
    const float* __restrict__ keys, const float* __restrict__ q,
    float* __restrict__ cd2, int* __restrict__ cidx)
{
  __shared__ float qs[NB * NE];
  int tid = threadIdx.x;
  for (int i = tid; i < NB * NE; i += 64) qs[i] = q[i];
  __syncthreads();
  int k = blockIdx.x * 64 + tid;
  const float4* kr = (const float4*)(keys + (size_t)k * NE);
  float d2[NB];
#pragma unroll
  for (int b = 0; b < NB; b++) d2[b] = 0.f;
  for (int e4 = 0; e4 < NE / 4; e4++) {
    float4 kv = kr[e4];
#pragma unroll
    for (int b = 0; b < NB; b++) {
      const float4* qv4 = (const float4*)(qs + b * NE);
      float4 qv = qv4[e4];
      float dx = kv.x - qv.x, dy = kv.y - qv.y, dz = kv.z - qv.z, dw = kv.w - qv.w;
      d2[b] += dx*dx + dy*dy + dz*dz + dw*dw;
    }
  }
#pragma unroll
  for (int b = 0; b < NB; b++) {
    float v = d2[b]; int idx = k;
    for (int off = 32; off > 0; off >>= 1) {
      float ov = __shfl_down(v, off);
      int   oi = __shfl_down(idx, off);
      if (ov < v || (ov == v && oi < idx)) { v = ov; idx = oi; }
    }
    if (tid == 0) { cd2[blockIdx.x * NB + b] = v; cidx[blockIdx.x * NB + b] = idx; }
  }
}

// ---- K7: final argmin + hit decision ---- 1 block x 64 thr
__global__ __launch_bounds__(64) void k_decide(
    const float* __restrict__ cd2, const int* __restrict__ cidx,
    const float* __restrict__ eps, int* __restrict__ hit, int* __restrict__ chosen)
{
  int tid = threadIdx.x;
  for (int b = 0; b < NB; b++) {
    float v = FLT_MAX; int idx = INT_MAX;
    if (tid < 32) { v = cd2[tid * NB + b]; idx = cidx[tid * NB + b]; }
    for (int off = 32; off > 0; off >>= 1) {
      float ov = __shfl_down(v, off);
      int   oi = __shfl_down(idx, off);
      if (ov < v || (ov == v && oi < idx)) { v = ov; idx = oi; }
    }
    if (tid == 0) {
      float dist = sqrtf(fmaxf(v, 0.f));
      chosen[b] = idx;
      hit[b] = (dist <= eps[idx]) ? 1 : 0;
    }
  }
}

// ---- K8: bf16 MFMA GEMM (M=8192,N=4096,K=4096) + fused bias/replace epilogue ----
// 128x128 tile, BK=64, 4 waves x 64x64, m97 2-barrier structure, global_load_lds x16.
__global__ __launch_bounds__(256) void k_gemm(
    const u16* __restrict__ A, const u16* __restrict__ Bw,
    const float* __restrict__ bias, const float* __restrict__ values,
    const int* __restrict__ hit, const int* __restrict__ chosen,
    float* __restrict__ out)
{
  __shared__ __align__(16) u16 As[128 * 64];
  __shared__ __align__(16) u16 Bs[128 * 64];
  int tid = threadIdx.x;
  size_t mbase = (size_t)blockIdx.y * 128;
  size_t nbase = (size_t)blockIdx.x * 128;
  int lane = tid & 63, wv = tid >> 6;
  int wm = (wv >> 1) * 64, wn = (wv & 1) * 64;
  int frow = lane & 15, fk = (lane >> 4) * 8;

  f32x4 acc[4][4] = {};

  for (int kt = 0; kt < ND; kt += 64) {
#pragma unroll
    for (int i = 0; i < 4; i++) {
      int c = i * 256 + tid;            // 16B chunk index; 8 chunks per 64-col row
      int row = c >> 3, col = (c & 7) * 8;
      gld_lds16(A  + (mbase + row) * ND + kt + col, &As[c * 8]);
      gld_lds16(Bw + (nbase + row) * ND + kt + col, &Bs[c * 8]);
    }
    __syncthreads();                    // compiler drains vmcnt before barrier
#pragma unroll
    for (int ks = 0; ks < 2; ks++) {
      bf16x8 af[4], bg[4];
      int ko = ks * 32 + fk;
#pragma unroll
      for (int mf = 0; mf < 4; mf++)
        af[mf] = *(const bf16x8*)&As[(wm + mf * 16 + frow) * 64 + ko];
#pragma unroll
      for (int nf = 0; nf < 4; nf++)
        bg[nf] = *(const bf16x8*)&Bs[(wn + nf * 16 + frow) * 64 + ko];
#pragma unroll
      for (int mf = 0; mf < 4; mf++)
#pragma unroll
        for (int nf = 0; nf < 4; nf++)
          mfma_bf16(acc[mf][nf], af[mf], bg[nf]);
    }
    __syncthreads();
  }

  // epilogue: C[m][o] layout col=lane&15, row=(lane>>4)*4+reg  [m89-verified]
  int smp = (int)(mbase >> 11);         // 128-row tile never crosses a sample
  int ht = hit[smp];
  const float* vrow = values + (size_t)chosen[smp] * ND;
  int r0 = (lane >> 4) * 4, c0 = lane & 15;
#pragma unroll
  for (int mf = 0; mf < 4; mf++) {
    size_t m = mbase + wm + mf * 16 + r0;
#pragma unroll
    for (int nf = 0; nf < 4; nf++) {
      size_t o = nbase + wn + nf * 16 + c0;
      float bia = bias[o];
      float rep = ht ? vrow[o] : 0.f;
#pragma unroll
      for (int r = 0; r < 4; r++) {
        float vvv = acc[mf][nf][r] + bia;
        out[(m + r) * ND + o] = ht ? rep : vvv;
      }
    }
  }
}

extern "C" void kernel_launch(void* const* d_in, const int* in_sizes, int n_in,
                              void* d_out, int out_size, void* d_ws, size_t ws_size,
                              hipStream_t stream) {
  const float* x      = (const float*)d_in[0];
  const float* W      = (const float*)d_in[1];
  const float* bias   = (const float*)d_in[2];
  const float* W1     = (const float*)d_in[3];
  const float* b1     = (const float*)d_in[4];
  const float* W2     = (const float*)d_in[5];
  const float* b2     = (const float*)d_in[6];
  const float* keys   = (const float*)d_in[7];
  const float* values = (const float*)d_in[8];
  const float* eps    = (const float*)d_in[9];
  float* out = (float*)d_out;
  char* ws = (char*)d_ws;

  u16*   xb     = (u16*)(ws + OFF_XB);
  u16*   wb     = (u16*)(ws + OFF_WB);
  int*   flags  = (int*)(ws + OFF_FLAGS);
  int*   first  = (int*)(ws + OFF_FIRST);
  float* inv    = (float*)(ws + OFF_INV);
  float* pooled = (float*)(ws + OFF_POOLED);
  float* h      = (float*)(ws + OFF_H);
  float* q      = (float*)(ws + OFF_Q);
  float* cd2    = (float*)(ws + OFF_CD2);
  int*   cidx   = (int*)(ws + OFF_CIDX);
  int*   hitp   = (int*)(ws + OFF_HIT);
  int*   chosenp= (int*)(ws + OFF_CHOSEN);

  hipMemsetAsync(pooled, 0, NB * ND * sizeof(float), stream);

  k_convert<<<NROWS + ND, 256, 0, stream>>>(x, W, xb, wb, flags);
  k_first  <<<1, 256, 0, stream>>>(flags, first, inv);
  k_pool   <<<256, 256, 0, stream>>>(x, first, pooled);
  k_enc1   <<<NE, 256, 0, stream>>>(pooled, inv, W1, b1, h);
  k_enc2   <<<1, 256, 0, stream>>>(h, W2, b2, q);
  k_dist   <<<NK / 64, 64, 0, stream>>>(keys, q, cd2, cidx);
  k_decide <<<1, 64, 0, stream>>>(cd2, cidx, eps, hitp, chosenp);

  dim3 gg(ND / 128, NROWS / 128);
  k_gemm<<<gg, 256, 0, stream>>>(xb, wb, bias, values, hitp, chosenp, out);
}

// Round 2
// 707.562 us; speedup vs baseline: 1.0485x; 1.0485x over previous
//
#include <hip/hip_runtime.h>
#include <cfloat>
#include <climits>

// layer_out = x@W^T + b; first-diff pooling; MLP encoder; kNN; replace-all epilogue.
// B=4 S=2048 D_IN=D_OUT=4096 ENC=256 K=2048, fp32 in/out.

typedef unsigned short u16;
typedef unsigned int   u32;
typedef unsigned long long u64;
typedef __attribute__((ext_vector_type(8))) short bf16x8;
typedef __attribute__((ext_vector_type(4))) float f32x4;
typedef __attribute__((address_space(3))) u32 as3u32;
typedef const __attribute__((address_space(1))) u32 as1u32;

#define NB 4
#define NS 2048
#define ND 4096
#define NE 256
#define NK 2048
#define NROWS (NB * NS)
#define NT 64            // K / 64 k-tiles in GEMM

// ---- workspace layout (bytes) ----
#define OFF_XB     ((size_t)0)            // 8192*4096 bf16 = 64 MiB
#define OFF_WB     ((size_t)67108864)     // 4096*4096 bf16 = 32 MiB
#define OFF_TS     ((size_t)100663296)    // 4*64*4096 f32 tile partial sums = 4 MiB
#define OFF_FLAGS  ((size_t)104857600)    // 8192 int
#define OFF_FIRST  ((size_t)104890368)    // 4 int
#define OFF_INV    ((size_t)104890384)    // 4 float
#define OFF_MINPK  ((size_t)104890400)    // 4 u64 (8-aligned)
#define OFF_POOLED ((size_t)104890432)    // 4*4096 f32
#define OFF_H      ((size_t)104955968)    // 4*256 f32

__device__ __forceinline__ void gld_lds16(const u16* g, u16* l) {
  __builtin_amdgcn_global_load_lds((as1u32*)g, (as3u32*)l, 16, 0, 0);
}

__device__ __forceinline__ u16 f2bf(float f) {   // RNE fp32 -> bf16
  union { float f; u32 u; } v; v.f = f;
  u32 r = v.u + 0x7fffu + ((v.u >> 16) & 1u);
  return (u16)(r >> 16);
}

__device__ __forceinline__ void mfma_bf16(f32x4& acc, bf16x8 a, bf16x8 b) {
  asm("v_mfma_f32_16x16x32_bf16 %0, %1, %2, %0" : "+v"(acc) : "v"(a), "v"(b));
}

// ---- K1: convert x->bf16 (+row-diff flags, +32-row tile partial sums) and W->bf16 ----
// blocks 0..255: x tiles (b = blk>>6, 32 rows each). blocks 256..511: W (16 rows each).
__global__ __launch_bounds__(256) void k_prep(
    const float* __restrict__ x, const float* __restrict__ W,
    u16* __restrict__ xb, u16* __restrict__ wb,
    int* __restrict__ flags, float* __restrict__ ts)
{
  int blk = blockIdx.x, tid = threadIdx.x;
  if (blk >= 256) {                       // ---- W rows ----
    int wr0 = (blk - 256) * 16;
    for (int i = 0; i < 16; i++) {
      const float* rp = W + (size_t)(wr0 + i) * ND;
      u16* op = wb + (size_t)(wr0 + i) * ND;
#pragma unroll
      for (int ch = 0; ch < 4; ch++) {
        int col = ch * 1024 + tid * 4;
        float4 v = *(const float4*)(rp + col);
        uint2 pk;
        pk.x = (u32)f2bf(v.x) | ((u32)f2bf(v.y) << 16);
        pk.y = (u32)f2bf(v.z) | ((u32)f2bf(v.w) << 16);
        *(uint2*)(op + col) = pk;
      }
    }
    return;
  }
  // ---- x tiles ----
  int b = blk >> 6, tile = blk & 63, s0 = tile * 32;
  __shared__ int rflag[32];
  if (tid < 32) rflag[tid] = 0;
  __syncthreads();
  float prev[16];
  bool havePrev = (s0 > 0);
  if (havePrev) {
    const float* pr = x + ((size_t)b * NS + s0 - 1) * ND;
#pragma unroll
    for (int ch = 0; ch < 4; ch++)
      *(float4*)&prev[ch * 4] = *(const float4*)(pr + ch * 1024 + tid * 4);
  }
  float tsa[16];
#pragma unroll
  for (int k = 0; k < 16; k++) tsa[k] = 0.f;
  for (int i = 0; i < 32; i++) {
    size_t row = (size_t)b * NS + s0 + i;
    const float* rp = x + row * ND;
    u16* op = xb + row * ND;
    float cur[16];
#pragma unroll
    for (int ch = 0; ch < 4; ch++) {
      int col = ch * 1024 + tid * 4;
      float4 v = *(const float4*)(rp + col);
      cur[ch*4+0] = v.x; cur[ch*4+1] = v.y; cur[ch*4+2] = v.z; cur[ch*4+3] = v.w;
      uint2 pk;
      pk.x = (u32)f2bf(v.x) | ((u32)f2bf(v.y) << 16);
      pk.y = (u32)f2bf(v.z) | ((u32)f2bf(v.w) << 16);
      *(uint2*)(op + col) = pk;
    }
    if (havePrev || i > 0) {
      bool d = false;
#pragma unroll
      for (int k = 0; k < 16; k++) d = d || (cur[k] != prev[k]);
      if (__any((int)d) && (tid & 63) == 0) atomicOr(&rflag[i], 1);
    }
#pragma unroll
    for (int k = 0; k < 16; k++) { tsa[k] += cur[k]; prev[k] = cur[k]; }
  }
  float* tsp = ts + (size_t)(b * 64 + tile) * ND;
#pragma unroll
  for (int ch = 0; ch < 4; ch++) {
    int col = ch * 1024 + tid * 4;
    float4 v; v.x = tsa[ch*4+0]; v.y = tsa[ch*4+1]; v.z = tsa[ch*4+2]; v.w = tsa[ch*4+3];
    *(float4*)(tsp + col) = v;
  }
  __syncthreads();
  if (tid < 32) flags[b * NS + s0 + tid] = rflag[tid];
}

// ---- K2: per-sample first-diff position + 1/count; init minpack ----
__global__ __launch_bounds__(256) void k_first(
    const int* __restrict__ flags, int* __restrict__ first, float* __restrict__ inv,
    u64* __restrict__ minpk)
{
  __shared__ int red[256];
  int tid = threadIdx.x;
  if (tid < NB) minpk[tid] = 0xFFFFFFFFFFFFFFFFull;
  for (int b = 0; b < NB; b++) {
    int best = INT_MAX;
    for (int j = 1 + tid; j < NS; j += 256)
      if (flags[b * NS + j] && j < best) best = j;
    red[tid] = best;
    __syncthreads();
    for (int st = 128; st > 0; st >>= 1) {
      if (tid < st && red[tid + st] < red[tid]) red[tid] = red[tid + st];
      __syncthreads();
    }
    if (tid == 0) {
      int f = red[0];
      if (f == INT_MAX) f = 0;
      if (f == 1) f = 0;
      first[b] = f;
      inv[b] = 1.0f / (float)(NS - f);
    }
    __syncthreads();
  }
}

// ---- K3: pooled mean from tile sums + boundary-row fixup (fp32 exact-ish) ----
__global__ __launch_bounds__(256) void k_poolfix(
    const float* __restrict__ x, const float* __restrict__ ts,
    const int* __restrict__ first, const float* __restrict__ inv,
    float* __restrict__ pooled)
{
  int b = blockIdx.x >> 2, seg = blockIdx.x & 3;
  int col = seg * 1024 + threadIdx.x * 4;
  int f = first[b], tf = f >> 5;
  float4 s = {0.f, 0.f, 0.f, 0.f};
  for (int t = tf; t < 64; t++) {
    float4 v = *(const float4*)(ts + (size_t)(b * 64 + t) * ND + col);
    s.x += v.x; s.y += v.y; s.z += v.z; s.w += v.w;
  }
  for (int r = tf * 32; r < f; r++) {
    float4 v = *(const float4*)(x + ((size_t)b * NS + r) * ND + col);
    s.x -= v.x; s.y -= v.y; s.z -= v.z; s.w -= v.w;
  }
  float iv = inv[b];
  float4 o; o.x = s.x * iv; o.y = s.y * iv; o.z = s.z * iv; o.w = s.w * iv;
  *(float4*)(pooled + (size_t)b * ND + col) = o;
}

// ---- K4: h = relu(pooled @ W1^T + b1) ---- 256 blocks (one per output) x 256 thr
__global__ __launch_bounds__(256) void k_enc1(
    const float* __restrict__ pooled,
    const float* __restrict__ W1, const float* __restrict__ b1, float* __restrict__ h)
{
  int o = blockIdx.x, tid = threadIdx.x;
  const float4* w4 = (const float4*)(W1 + (size_t)o * ND);
  float4 w[4];
#pragma unroll
  for (int i = 0; i < 4; i++) w[i] = w4[tid * 4 + i];
  float part[NB];
#pragma unroll
  for (int b = 0; b < NB; b++) {
    const float4* p4 = (const float4*)(pooled + (size_t)b * ND);
    float s = 0.f;
#pragma unroll
    for (int i = 0; i < 4; i++) {
      float4 p = p4[tid * 4 + i];
      s += w[i].x*p.x + w[i].y*p.y + w[i].z*p.z + w[i].w*p.w;
    }
    part[b] = s;
  }
  __shared__ float red[NB][4];
  int lane = tid & 63, wvv = tid >> 6;
#pragma unroll
  for (int b = 0; b < NB; b++) {
    float v = part[b];
    for (int off = 32; off > 0; off >>= 1) v += __shfl_down(v, off);
    if (lane == 0) red[b][wvv] = v;
  }
  __syncthreads();
  if (tid < NB) {
    float s = red[tid][0] + red[tid][1] + red[tid][2] + red[tid][3];
    h[tid * NE + o] = fmaxf(s + b1[o], 0.f);
  }
}

// ---- K5: enc2 (q = h@W2^T + b2) + key distances + packed atomicMin argmin ----
__global__ __launch_bounds__(256) void k_dist2(
    const float* __restrict__ h, const float* __restrict__ W2,
    const float* __restrict__ b2, const float* __restrict__ keys,
    u64* __restrict__ minpk)
{
  __shared__ float hs[NB * NE];
  __shared__ float qs[NB][NE];
  int tid = threadIdx.x;
  for (int i = tid; i < NB * NE; i += 256) hs[i] = h[i];
  __syncthreads();
  {
    const float4* w4 = (const float4*)(W2 + (size_t)tid * NE);
    float bb = b2[tid];
    float s0 = bb, s1 = bb, s2 = bb, s3 = bb;
    for (int e4 = 0; e4 < NE / 4; e4++) {
      float4 wv = w4[e4];
      float4 a0 = ((const float4*)(hs))[e4];
      float4 a1 = ((const float4*)(hs + NE))[e4];
      float4 a2 = ((const float4*)(hs + 2 * NE))[e4];
      float4 a3 = ((const float4*)(hs + 3 * NE))[e4];
      s0 += wv.x*a0.x + wv.y*a0.y + wv.z*a0.z + wv.w*a0.w;
      s1 += wv.x*a1.x + wv.y*a1.y + wv.z*a1.z + wv.w*a1.w;
      s2 += wv.x*a2.x + wv.y*a2.y + wv.z*a2.z + wv.w*a2.w;
      s3 += wv.x*a3.x + wv.y*a3.y + wv.z*a3.z + wv.w*a3.w;
    }
    qs[0][tid] = s0; qs[1][tid] = s1; qs[2][tid] = s2; qs[3][tid] = s3;
  }
  __syncthreads();
  if (tid < 64) {
    int k = blockIdx.x * 64 + tid;
    const float4* kr = (const float4*)(keys + (size_t)k * NE);
    float d2[NB] = {0.f, 0.f, 0.f, 0.f};
    for (int e4 = 0; e4 < NE / 4; e4++) {
      float4 kv = kr[e4];
#pragma unroll
      for (int b = 0; b < NB; b++) {
        float4 qv = ((const float4*)&qs[b][0])[e4];
        float dx = kv.x - qv.x, dy = kv.y - qv.y, dz = kv.z - qv.z, dw = kv.w - qv.w;
        d2[b] += dx*dx + dy*dy + dz*dz + dw*dw;
      }
    }
#pragma unroll
    for (int b = 0; b < NB; b++) {
      float v = d2[b]; int idx = k;
      for (int off = 32; off > 0; off >>= 1) {
        float ov = __shfl_down(v, off);
        int   oi = __shfl_down(idx, off);
        if (ov < v || (ov == v && oi < idx)) { v = ov; idx = oi; }
      }
      if (tid == 0)
        atomicMin(&minpk[b], ((u64)__float_as_uint(v) << 32) | (u32)idx);
    }
  }
}

// ---- K6: 256x256 8-phase bf16 MFMA GEMM + fused decide/bias/replace epilogue ----
// 512 thr = 8 waves (2M x 4N), per-wave 128x64 out. LDS: K-half slots [256][32],
// double-buffered = 128 KiB. 1 half-tile staged/phase into the just-freed slot;
// boundary vmcnt(6). Swizzle: 16B-chunk ^= (row>>1)&3 (pre-swizzled global src).
__device__ __forceinline__ void stage_half(const u16* __restrict__ mat, size_t rowbase,
                                           u16* slot, int ktile, int kh, int tid) {
  int wv = tid >> 6, lane = tid & 63;
#pragma unroll
  for (int r = 0; r < 2; r++) {
    int ci = wv + 8 * r;
    int lrow = ci * 16 + (lane >> 2);
    int kc = (lane & 3) ^ ((lrow >> 1) & 3);
    const u16* src = mat + (rowbase + lrow) * ND + (ktile * 64 + kh * 32 + kc * 8);
    gld_lds16(src, slot + ci * 512 + lane * 8);
  }
}

__device__ __forceinline__ bf16x8 ld_frag(const u16* slot, int row, int kc) {
  int chunk = kc ^ ((row >> 1) & 3);
  return *(const bf16x8*)(slot + row * 32 + chunk * 8);
}

__global__ __launch_bounds__(512, 2) void k_gemm(
    const u16* __restrict__ A, const u16* __restrict__ Bw,
    const float* __restrict__ bias, const float* __restrict__ values,
    const u64* __restrict__ minpk, const float* __restrict__ eps,
    float* __restrict__ out)
{
  __shared__ __align__(16) u16 As[2][2][256 * 32];
  __shared__ __align__(16) u16 Bs[2][2][256 * 32];
  int tid = threadIdx.x, lane = tid & 63, wv = tid >> 6;
  size_t mbase = (size_t)blockIdx.y * 256;
  size_t nbase = (size_t)blockIdx.x * 256;
  int wm = (wv >> 2) * 128, wn = (wv & 3) * 64;
  int frow = lane & 15, fkc = lane >> 4;

  f32x4 acc[8][4] = {};

  // prologue: tile0 {B0,A0,B1,A1}, tile1 {B0,A0,B1}  (ring order)
  stage_half(Bw, nbase, Bs[0][0], 0, 0, tid);
  stage_half(A,  mbase, As[0][0], 0, 0, tid);
  stage_half(Bw, nbase, Bs[0][1], 0, 1, tid);
  stage_half(A,  mbase, As[0][1], 0, 1, tid);
  stage_half(Bw, nbase, Bs[1][0], 1, 0, tid);
  stage_half(A,  mbase, As[1][0], 1, 0, tid);
  stage_half(Bw, nbase, Bs[1][1], 1, 1, tid);
  asm volatile("s_waitcnt vmcnt(6)" ::: "memory");
  __builtin_amdgcn_s_barrier();

  bf16x8 afr[4], bfr[4];
  for (int t = 0; t < NT; t++) {
    int c = t & 1;
    int kt1 = (t + 1 < NT) ? t + 1 : NT - 1;   // clamped: dup loads land in dead slots
    int kt2 = (t + 2 < NT) ? t + 2 : NT - 1;
    const u16* Ac0 = As[c][0]; const u16* Ac1 = As[c][1];
    const u16* Bc0 = Bs[c][0]; const u16* Bc1 = Bs[c][1];

    // ---- ph1: m0-3 x ks0 ---- (reads A0,B0; stages (t+1).A1 -> other buffer)
#pragma unroll
    for (int mf = 0; mf < 4; mf++) afr[mf] = ld_frag(Ac0, wm + mf * 16 + frow, fkc);
#pragma unroll
    for (int nf = 0; nf < 4; nf++) bfr[nf] = ld_frag(Bc0, wn + nf * 16 + frow, fkc);
    stage_half(A, mbase, As[c ^ 1][1], kt1, 1, tid);
    __builtin_amdgcn_s_barrier();
    asm volatile("s_waitcnt lgkmcnt(0)" ::: "memory");
    __builtin_amdgcn_sched_barrier(0);
    __builtin_amdgcn_s_setprio(1);
#pragma unroll
    for (int mf = 0; mf < 4; mf++)
#pragma unroll
      for (int nf = 0; nf < 4; nf++) mfma_bf16(acc[mf][nf], afr[mf], bfr[nf]);
    __builtin_amdgcn_s_setprio(0);
    __builtin_amdgcn_s_barrier();

    // ---- ph2: m4-7 x ks0 ---- (reads A0; B0 regs reused; stages (t+2).B0 -> freed slot)
#pragma unroll
    for (int mf = 0; mf < 4; mf++) afr[mf] = ld_frag(Ac0, wm + 64 + mf * 16 + frow, fkc);
    stage_half(Bw, nbase, Bs[c][0], kt2, 0, tid);
    __builtin_amdgcn_s_barrier();
    asm volatile("s_waitcnt lgkmcnt(0)" ::: "memory");
    __builtin_amdgcn_sched_barrier(0);
    __builtin_amdgcn_s_setprio(1);
#pragma unroll
    for (int mf = 0; mf < 4; mf++)
#pragma unroll
      for (int nf = 0; nf < 4; nf++) mfma_bf16(acc[4 + mf][nf], afr[mf], bfr[nf]);
    __builtin_amdgcn_s_setprio(0);
    __builtin_amdgcn_s_barrier();

    // ---- ph3: m0-3 x ks1 ---- (reads A1,B1; stages (t+2).A0)
#pragma unroll
    for (int mf = 0; mf < 4; mf++) afr[mf] = ld_frag(Ac1, wm + mf * 16 + frow, fkc);
#pragma unroll
    for (int nf = 0; nf < 4; nf++) bfr[nf] = ld_frag(Bc1, wn + nf * 16 + frow, fkc);
    stage_half(A, mbase, As[c][0], kt2, 0, tid);
    __builtin_amdgcn_s_barrier();
    asm volatile("s_waitcnt lgkmcnt(0)" ::: "memory");
    __builtin_amdgcn_sched_barrier(0);
    __builtin_amdgcn_s_setprio(1);
#pragma unroll
    for (int mf = 0; mf < 4; mf++)
#pragma unroll
      for (int nf = 0; nf < 4; nf++) mfma_bf16(acc[mf][nf], afr[mf], bfr[nf]);
    __builtin_amdgcn_s_setprio(0);
    __builtin_amdgcn_s_barrier();

    // ---- ph4: m4-7 x ks1 ---- (reads A1; stages (t+2).B1; boundary vmcnt(6))
#pragma unroll
    for (int mf = 0; mf < 4; mf++) afr[mf] = ld_frag(Ac1, wm + 64 + mf * 16 + frow, fkc);
    stage_half(Bw, nbase, Bs[c][1], kt2, 1, tid);
    __builtin_amdgcn_s_barrier();
    asm volatile("s_waitcnt lgkmcnt(0)" ::: "memory");
    __builtin_amdgcn_sched_barrier(0);
    __builtin_amdgcn_s_setprio(1);
#pragma unroll
    for (int mf = 0; mf < 4; mf++)
#pragma unroll
      for (int nf = 0; nf < 4; nf++) mfma_bf16(acc[4 + mf][nf], afr[mf], bfr[nf]);
    __builtin_amdgcn_s_setprio(0);
    asm volatile("s_waitcnt vmcnt(6)" ::: "memory");
    __builtin_amdgcn_s_barrier();
  }

  // ---- epilogue: decide + bias/replace; C layout col=lane&15, row=(lane>>4)*4+reg ----
  u64 pk = minpk[mbase >> 11];                 // 256-row tile never crosses a sample
  float d2 = __uint_as_float((u32)(pk >> 32));
  int idx = (int)(pk & 0xFFFFFFFFull);
  int ht = (sqrtf(fmaxf(d2, 0.f)) <= eps[idx]) ? 1 : 0;
  const float* vrow = values + (size_t)idx * ND;
  int r0 = (lane >> 4) * 4, c0 = lane & 15;
#pragma unroll
  for (int mf = 0; mf < 8; mf++) {
    size_t m = mbase + wm + mf * 16 + r0;
#pragma unroll
    for (int nf = 0; nf < 4; nf++) {
      size_t o = nbase + wn + nf * 16 + c0;
      float bia = bias[o];
      float rep = ht ? vrow[o] : 0.f;
#pragma unroll
      for (int r = 0; r < 4; r++)
        out[(m + r) * ND + o] = ht ? rep : (acc[mf][nf][r] + bia);
    }
  }
}

extern "C" void kernel_launch(void* const* d_in, const int* in_sizes, int n_in,
                              void* d_out, int out_size, void* d_ws, size_t ws_size,
                              hipStream_t stream) {
  const float* x      = (const float*)d_in[0];
  const float* W      = (const float*)d_in[1];
  const float* bias   = (const float*)d_in[2];
  const float* W1     = (const float*)d_in[3];
  const float* b1     = (const float*)d_in[4];
  const float* W2     = (const float*)d_in[5];
  const float* b2     = (const float*)d_in[6];
  const float* keys   = (const float*)d_in[7];
  const float* values = (const float*)d_in[8];
  const float* eps    = (const float*)d_in[9];
  float* out = (float*)d_out;
  char* ws = (char*)d_ws;

  u16*   xb     = (u16*)(ws + OFF_XB);
  u16*   wb     = (u16*)(ws + OFF_WB);
  float* ts     = (float*)(ws + OFF_TS);
  int*   flags  = (int*)(ws + OFF_FLAGS);
  int*   first  = (int*)(ws + OFF_FIRST);
  float* inv    = (float*)(ws + OFF_INV);
  u64*   minpk  = (u64*)(ws + OFF_MINPK);
  float* pooled = (float*)(ws + OFF_POOLED);
  float* h      = (float*)(ws + OFF_H);

  k_prep   <<<512, 256, 0, stream>>>(x, W, xb, wb, flags, ts);
  k_first  <<<1, 256, 0, stream>>>(flags, first, inv, minpk);
  k_poolfix<<<16, 256, 0, stream>>>(x, ts, first, inv, pooled);
  k_enc1   <<<NE, 256, 0, stream>>>(pooled, W1, b1, h);
  k_dist2  <<<NK / 64, 256, 0, stream>>>(h, W2, b2, keys, minpk);

  dim3 gg(ND / 256, NROWS / 256);
  k_gemm<<<gg, 512, 0, stream>>>(xb, wb, bias, values, minpk, eps, out);
}